// Round 2
// baseline (948.701 us; speedup 1.0000x reference)
//
#include <hip/hip_runtime.h>
#include <math.h>

#define NROWS 8192
#define DIM 128
#define BM 64
#define BN 64
#define TEMP_INV 2.0f   // 1 / TEMPERATURE

// ---------------- init: zero accumulators in workspace ----------------
__global__ void k_init(float* __restrict__ negsum, int* __restrict__ hist,
                       float* __restrict__ losssum) {
  int t = blockIdx.x * blockDim.x + threadIdx.x;
  if (t < NROWS) negsum[t] = 0.f;
  if (t < 10) hist[t] = 0;
  if (t == 0) losssum[0] = 0.f;
}

// ---------------- normalize rows + label histogram ----------------
// one wave (64 lanes) per row; each lane holds 2 of the 128 elements
__global__ __launch_bounds__(256) void k_norm(const float* __restrict__ f,
                                              const int* __restrict__ lab,
                                              float* __restrict__ fn,
                                              int* __restrict__ hist) {
  int wave = threadIdx.x >> 6;
  int lane = threadIdx.x & 63;
  int row = blockIdx.x * 4 + wave;
  const float* src = f + (size_t)row * DIM;
  float v0 = src[lane];
  float v1 = src[lane + 64];
  float ss = v0 * v0 + v1 * v1;
#pragma unroll
  for (int o = 32; o > 0; o >>= 1) ss += __shfl_down(ss, o);
  ss = __shfl(ss, 0);
  float inv = 1.0f / fmaxf(sqrtf(ss), 1e-8f);
  float* dst = fn + (size_t)row * DIM;
  dst[lane] = v0 * inv;
  dst[lane + 64] = v1 * inv;
  if (lane == 0) atomicAdd(&hist[lab[row]], 1);
}

// ---------------- pairwise tile kernel ----------------
// PASS 1: accumulate negsum[i] = sum_{j: lab_j != lab_i} exp(2*sim_ij)
// PASS 2: accumulate loss_sum = sum_{(i,j) pos} log(1 + negtot[i]*exp(-2*sim_ij))
template <int PASS>
__global__ __launch_bounds__(256) void k_pairs(const float* __restrict__ fn,
                                               const int* __restrict__ lab,
                                               float* __restrict__ negsum,
                                               const int* __restrict__ hist,
                                               float* __restrict__ losssum) {
  __shared__ float As[BM][DIM + 1];
  __shared__ float Bs[BN][DIM + 1];

  const int t = threadIdx.x;
  const int tx = t & 15;
  const int ty = t >> 4;
  const int i0 = blockIdx.y * BM;
  const int j0 = blockIdx.x * BN;

  // stage tiles: 256 threads x 8 iters x float4 covers 64x128 per matrix
#pragma unroll
  for (int it = 0; it < 8; ++it) {
    int q = t + 256 * it;     // 0..2047
    int row = q >> 5;         // /32
    int c4 = (q & 31) << 2;   // float4 column
    float4 a = *reinterpret_cast<const float4*>(&fn[(size_t)(i0 + row) * DIM + c4]);
    As[row][c4 + 0] = a.x; As[row][c4 + 1] = a.y;
    As[row][c4 + 2] = a.z; As[row][c4 + 3] = a.w;
    float4 b = *reinterpret_cast<const float4*>(&fn[(size_t)(j0 + row) * DIM + c4]);
    Bs[row][c4 + 0] = b.x; Bs[row][c4 + 1] = b.y;
    Bs[row][c4 + 2] = b.z; Bs[row][c4 + 3] = b.w;
  }
  __syncthreads();

  // 4x4 register tile per thread
  float acc[4][4] = {};
#pragma unroll 4
  for (int k = 0; k < DIM; ++k) {
    float a[4], b[4];
#pragma unroll
    for (int u = 0; u < 4; ++u) a[u] = As[ty * 4 + u][k];
#pragma unroll
    for (int v = 0; v < 4; ++v) b[v] = Bs[tx * 4 + v][k];
#pragma unroll
    for (int u = 0; u < 4; ++u)
#pragma unroll
      for (int v = 0; v < 4; ++v) acc[u][v] = fmaf(a[u], b[v], acc[u][v]);
  }

  int labr[4], labc[4];
#pragma unroll
  for (int u = 0; u < 4; ++u) labr[u] = lab[i0 + ty * 4 + u];
#pragma unroll
  for (int v = 0; v < 4; ++v) labc[v] = lab[j0 + tx * 4 + v];

  __syncthreads();  // tiles no longer needed; reuse Bs as reduction scratch

  if (PASS == 1) {
    float rowsum[4] = {0.f, 0.f, 0.f, 0.f};
#pragma unroll
    for (int u = 0; u < 4; ++u)
#pragma unroll
      for (int v = 0; v < 4; ++v)
        if (labr[u] != labc[v]) rowsum[u] += __expf(TEMP_INV * acc[u][v]);

    float(*red)[16] = reinterpret_cast<float(*)[16]>(&Bs[0][0]);
#pragma unroll
    for (int u = 0; u < 4; ++u) red[ty * 4 + u][tx] = rowsum[u];
    __syncthreads();
    if (t < BM) {
      float s = 0.f;
#pragma unroll
      for (int x = 0; x < 16; ++x) s += red[t][(x + t) & 15];  // rotate: spread banks
      atomicAdd(&negsum[i0 + t], s);
    }
  } else {
    float nt[4];
#pragma unroll
    for (int u = 0; u < 4; ++u)
      nt[u] = negsum[i0 + ty * 4 + u] + (float)hist[labr[u]];

    float lsum = 0.f;
#pragma unroll
    for (int u = 0; u < 4; ++u)
#pragma unroll
      for (int v = 0; v < 4; ++v)
        if (labr[u] == labc[v])
          lsum += __logf(1.0f + nt[u] * __expf(-TEMP_INV * acc[u][v]));

    float* flat = &Bs[0][0];
    flat[t] = lsum;
    __syncthreads();
    for (int s2 = 128; s2 > 0; s2 >>= 1) {
      if (t < s2) flat[t] += flat[t + s2];
      __syncthreads();
    }
    if (t == 0) atomicAdd(losssum, flat[0]);
  }
}

// ---------------- finalize: loss = loss_sum / num_pos ----------------
__global__ void k_final(const float* __restrict__ losssum, const int* __restrict__ hist,
                        float* __restrict__ out) {
  if (threadIdx.x == 0) {
    double np = 0.0;
    for (int c = 0; c < 10; ++c) np += (double)hist[c] * (double)hist[c];
    out[0] = (float)((double)losssum[0] / np);
  }
}

extern "C" void kernel_launch(void* const* d_in, const int* in_sizes, int n_in,
                              void* d_out, int out_size, void* d_ws, size_t ws_size,
                              hipStream_t stream) {
  const float* feat = (const float*)d_in[0];
  const int* lab = (const int*)d_in[1];
  float* out = (float*)d_out;

  char* ws = (char*)d_ws;
  float* fn = (float*)ws;                               // 8192*128*4 = 4 MiB
  float* negsum = (float*)(ws + (size_t)NROWS * DIM * 4);  // 32 KiB
  int* hist = (int*)(ws + (size_t)NROWS * DIM * 4 + NROWS * 4);
  float* losssum = (float*)(ws + (size_t)NROWS * DIM * 4 + NROWS * 4 + 64);

  k_init<<<32, 256, 0, stream>>>(negsum, hist, losssum);
  k_norm<<<NROWS / 4, 256, 0, stream>>>(feat, lab, fn, hist);
  dim3 grid(NROWS / BN, NROWS / BM);
  k_pairs<1><<<grid, 256, 0, stream>>>(fn, lab, negsum, hist, losssum);
  k_pairs<2><<<grid, 256, 0, stream>>>(fn, lab, negsum, hist, losssum);
  k_final<<<1, 64, 0, stream>>>(losssum, hist, out);
}

// Round 3
// 153.251 us; speedup vs baseline: 6.1905x; 6.1905x over previous
//
#include <hip/hip_runtime.h>
#include <hip/hip_bf16.h>
#include <math.h>

#define NROWS 8192
#define DIM 128
#define BM 128                        // rows per block tile
#define BN 128                        // cols per inner tile
#define CS 8                          // column slabs
#define COLS_PER_SLAB (NROWS / CS)    // 1024
#define CT_ITERS (COLS_PER_SLAB / BN) // 8
#define RS (NROWS / BM)               // 64

typedef __attribute__((ext_vector_type(8))) short bf16x8;
typedef __attribute__((ext_vector_type(4))) float f32x4;

// ---------------- init: zero hist + losssum ----------------
__global__ void k_init(int* __restrict__ hist, float* __restrict__ losssum) {
  int t = threadIdx.x;
  if (t < 10) hist[t] = 0;
  if (t == 0) losssum[0] = 0.f;
}

// ---------------- normalize rows -> bf16, label histogram ----------------
__global__ __launch_bounds__(256) void k_norm(const float* __restrict__ f,
                                              const int* __restrict__ lab,
                                              __hip_bfloat16* __restrict__ fnb,
                                              int* __restrict__ hist) {
  int wave = threadIdx.x >> 6;
  int lane = threadIdx.x & 63;
  int row = blockIdx.x * 4 + wave;
  const float* src = f + (size_t)row * DIM;
  float v0 = src[lane];
  float v1 = src[lane + 64];
  float ss = v0 * v0 + v1 * v1;
#pragma unroll
  for (int o = 32; o > 0; o >>= 1) ss += __shfl_down(ss, o);
  ss = __shfl(ss, 0);
  float inv = 1.0f / fmaxf(sqrtf(ss), 1e-8f);
  __hip_bfloat16* dst = fnb + (size_t)row * DIM;
  dst[lane] = __float2bfloat16(v0 * inv);
  dst[lane + 64] = __float2bfloat16(v1 * inv);
  if (lane == 0) atomicAdd(&hist[lab[row]], 1);
}

// ---------------- single MFMA pass ----------------
// Block (cs, rsb): rows [rsb*128, +128), cols [cs*1024, +1024) in 8 tiles of 128.
// Per row accumulate: negsum (lab!=), possumE, possumE2, simacc (sum of raw cos dot).
__global__ __launch_bounds__(256, 2) void k_main(
    const ushort* __restrict__ fnb, const int* __restrict__ lab,
    float* __restrict__ pneg, float* __restrict__ ppos,
    float* __restrict__ ppos2, float* __restrict__ psim) {
  __shared__ char lds[BM * 256 + BN * 256];  // A (32KB) + B (32KB), swizzled
  char* Alds = lds;
  char* Blds = lds + BM * 256;

  const int t = threadIdx.x;
  const int lane = t & 63;
  const int w = t >> 6;
  const int wm = w >> 1;  // 0..1  (row half)
  const int wn = w & 1;   // 0..1  (col half)
  const int cs = blockIdx.x;
  const int i0 = blockIdx.y * BM;

  // ---- stage A once (rows i0..i0+127), XOR-swizzled (G4: row-major D=128 bf16) ----
  {
    const int4* src = reinterpret_cast<const int4*>(fnb + (size_t)i0 * DIM);
#pragma unroll
    for (int it = 0; it < 8; ++it) {
      int q = t + 256 * it;       // 0..2047 16B-chunks
      int row = q >> 4, c = q & 15;
      int4 v = src[q];
      *reinterpret_cast<int4*>(Alds + row * 256 + ((c << 4) ^ ((row & 7) << 4))) = v;
    }
  }

  // row labels for this thread's C fragment rows: row = wm*64 + m*16 + (lane>>4)*4 + r
  int lr[4][4];
#pragma unroll
  for (int m = 0; m < 4; ++m)
#pragma unroll
    for (int r = 0; r < 4; ++r)
      lr[m][r] = lab[i0 + wm * 64 + m * 16 + (lane >> 4) * 4 + r];

  float a_neg[4][4] = {}, a_pos[4][4] = {}, a_pos2[4][4] = {}, a_sim[4][4] = {};

  for (int ct = 0; ct < CT_ITERS; ++ct) {
    const int j0 = cs * COLS_PER_SLAB + ct * BN;
    __syncthreads();  // protect Blds from previous iteration's readers
    {
      const int4* src = reinterpret_cast<const int4*>(fnb + (size_t)j0 * DIM);
#pragma unroll
      for (int it = 0; it < 8; ++it) {
        int q = t + 256 * it;
        int row = q >> 4, c = q & 15;
        int4 v = src[q];
        *reinterpret_cast<int4*>(Blds + row * 256 + ((c << 4) ^ ((row & 7) << 4))) = v;
      }
    }
    __syncthreads();

    f32x4 acc[4][4];
#pragma unroll
    for (int m = 0; m < 4; ++m)
#pragma unroll
      for (int n = 0; n < 4; ++n) acc[m][n] = (f32x4){0.f, 0.f, 0.f, 0.f};

#pragma unroll
    for (int ks = 0; ks < 4; ++ks) {
      const int kb = ks * 64 + ((lane >> 4) << 4);  // 16B chunk within 256B row
      bf16x8 af[4], bf[4];
#pragma unroll
      for (int m = 0; m < 4; ++m) {
        int r = wm * 64 + m * 16 + (lane & 15);
        af[m] = *reinterpret_cast<const bf16x8*>(Alds + r * 256 + (kb ^ ((r & 7) << 4)));
      }
#pragma unroll
      for (int n = 0; n < 4; ++n) {
        int r = wn * 64 + n * 16 + (lane & 15);
        bf[n] = *reinterpret_cast<const bf16x8*>(Blds + r * 256 + (kb ^ ((r & 7) << 4)));
      }
#pragma unroll
      for (int m = 0; m < 4; ++m)
#pragma unroll
        for (int n = 0; n < 4; ++n)
          acc[m][n] = __builtin_amdgcn_mfma_f32_16x16x32_bf16(af[m], bf[n], acc[m][n], 0, 0, 0);
    }

    // epilogue: accumulate per-row stats in registers (C: col=lane&15, row=(lane>>4)*4+r)
#pragma unroll
    for (int n = 0; n < 4; ++n) {
      const int lc = lab[j0 + wn * 64 + n * 16 + (lane & 15)];
#pragma unroll
      for (int m = 0; m < 4; ++m)
#pragma unroll
        for (int r = 0; r < 4; ++r) {
          float s = acc[m][n][r];           // cos sim (sim = 2*s)
          float E = __expf(2.0f * s);
          bool pos = (lr[m][r] == lc);
          a_neg[m][r] += pos ? 0.f : E;
          a_pos[m][r] += pos ? E : 0.f;
          a_pos2[m][r] += pos ? E * E : 0.f;
          a_sim[m][r] += pos ? s : 0.f;
        }
    }
  }

  // reduce across the 16 lanes of each row group (cols), then across wn waves via LDS
#pragma unroll
  for (int m = 0; m < 4; ++m)
#pragma unroll
    for (int r = 0; r < 4; ++r)
#pragma unroll
      for (int off = 8; off > 0; off >>= 1) {
        a_neg[m][r] += __shfl_xor(a_neg[m][r], off);
        a_pos[m][r] += __shfl_xor(a_pos[m][r], off);
        a_pos2[m][r] += __shfl_xor(a_pos2[m][r], off);
        a_sim[m][r] += __shfl_xor(a_sim[m][r], off);
      }

  __syncthreads();  // done with A/B tiles; reuse LDS as reduction scratch
  float* red = reinterpret_cast<float*>(lds);  // [128 rows][4]
  const int g = lane >> 4;
  if (wn == 1 && (lane & 15) == 0) {
#pragma unroll
    for (int m = 0; m < 4; ++m)
#pragma unroll
      for (int r = 0; r < 4; ++r) {
        int rl = wm * 64 + m * 16 + g * 4 + r;
        red[rl * 4 + 0] = a_neg[m][r];
        red[rl * 4 + 1] = a_pos[m][r];
        red[rl * 4 + 2] = a_pos2[m][r];
        red[rl * 4 + 3] = a_sim[m][r];
      }
  }
  __syncthreads();
  if (wn == 0 && (lane & 15) == 0) {
#pragma unroll
    for (int m = 0; m < 4; ++m)
#pragma unroll
      for (int r = 0; r < 4; ++r) {
        int rl = wm * 64 + m * 16 + g * 4 + r;
        int row = i0 + rl;
        pneg[cs * NROWS + row] = a_neg[m][r] + red[rl * 4 + 0];
        ppos[cs * NROWS + row] = a_pos[m][r] + red[rl * 4 + 1];
        ppos2[cs * NROWS + row] = a_pos2[m][r] + red[rl * 4 + 2];
        psim[cs * NROWS + row] = a_sim[m][r] + red[rl * 4 + 3];
      }
  }
}

// ---------------- per-row finalize + global sum ----------------
__global__ __launch_bounds__(1024) void k_rowfinal(
    const float* __restrict__ pneg, const float* __restrict__ ppos,
    const float* __restrict__ ppos2, const float* __restrict__ psim,
    const int* __restrict__ lab, const int* __restrict__ hist,
    float* __restrict__ losssum) {
  __shared__ float sred[1024];
  int i = blockIdx.x * 1024 + threadIdx.x;
  float ns = 0.f, ps = 0.f, ps2 = 0.f, sa = 0.f;
#pragma unroll
  for (int cs = 0; cs < CS; ++cs) {
    ns += pneg[cs * NROWS + i];
    ps += ppos[cs * NROWS + i];
    ps2 += ppos2[cs * NROWS + i];
    sa += psim[cs * NROWS + i];
  }
  float cnt = (float)hist[lab[i]];
  float negtot = ns + cnt;  // positives contribute exp(0)=1 each to exp_neg
  // sum over positives: log(negtot) + log1p(E/negtot) - sim,  E=exp(2*cos), sim=2*cos
  float li = cnt * logf(negtot) - 2.f * sa + ps / negtot - ps2 / (2.f * negtot * negtot);
  sred[threadIdx.x] = li;
  __syncthreads();
  for (int s2 = 512; s2 > 0; s2 >>= 1) {
    if (threadIdx.x < s2) sred[threadIdx.x] += sred[threadIdx.x + s2];
    __syncthreads();
  }
  if (threadIdx.x == 0) atomicAdd(losssum, sred[0]);
}

// ---------------- output ----------------
__global__ void k_out(const float* __restrict__ losssum, const int* __restrict__ hist,
                      float* __restrict__ out) {
  if (threadIdx.x == 0) {
    double np = 0.0;
    for (int c = 0; c < 10; ++c) np += (double)hist[c] * (double)hist[c];
    out[0] = (float)((double)losssum[0] / np);
  }
}

extern "C" void kernel_launch(void* const* d_in, const int* in_sizes, int n_in,
                              void* d_out, int out_size, void* d_ws, size_t ws_size,
                              hipStream_t stream) {
  const float* feat = (const float*)d_in[0];
  const int* lab = (const int*)d_in[1];
  float* out = (float*)d_out;

  char* ws = (char*)d_ws;
  __hip_bfloat16* fnb = (__hip_bfloat16*)ws;               // 2 MiB
  size_t off = (size_t)NROWS * DIM * 2;
  float* pneg = (float*)(ws + off);  off += (size_t)CS * NROWS * 4;   // 256 KiB
  float* ppos = (float*)(ws + off);  off += (size_t)CS * NROWS * 4;
  float* ppos2 = (float*)(ws + off); off += (size_t)CS * NROWS * 4;
  float* psim = (float*)(ws + off);  off += (size_t)CS * NROWS * 4;
  int* hist = (int*)(ws + off);      off += 64;
  float* losssum = (float*)(ws + off);

  k_init<<<1, 64, 0, stream>>>(hist, losssum);
  k_norm<<<NROWS / 4, 256, 0, stream>>>(feat, lab, fnb, hist);
  dim3 grid(CS, RS);
  k_main<<<grid, 256, 0, stream>>>((const ushort*)fnb, lab, pneg, ppos, ppos2, psim);
  k_rowfinal<<<NROWS / 1024, 1024, 0, stream>>>(pneg, ppos, ppos2, psim, lab, hist, losssum);
  k_out<<<1, 64, 0, stream>>>(losssum, hist, out);
}

// Round 5
// 60.531 us; speedup vs baseline: 15.6731x; 2.5318x over previous
//
#include <hip/hip_runtime.h>
#include <hip/hip_bf16.h>
#include <math.h>

#define NROWS 8192
#define DIM 128
#define BM 128                        // rows per block tile
#define BN 128                        // cols per inner tile
#define CS 8                          // column slabs
#define COLS_PER_SLAB (NROWS / CS)    // 1024
#define CT_ITERS (COLS_PER_SLAB / BN) // 8
#define RS (NROWS / BM)               // 64

typedef __attribute__((ext_vector_type(8))) short bf16x8;
typedef __attribute__((ext_vector_type(4))) float f32x4;

// ---------------- label histogram (single block, LDS sub-hists, NO global atomics)
// also zeroes losssum (stream-ordered before k_rowfinal)
__global__ __launch_bounds__(1024) void k_hist(const int* __restrict__ lab,
                                               int* __restrict__ hist,
                                               float* __restrict__ losssum) {
  __shared__ int sh[16][16];  // 16 waves x 10 bins (padded to 16)
  const int t = threadIdx.x;
  const int w = t >> 6;
  if ((t & 63) < 16) sh[w][t & 63] = 0;
  __syncthreads();
#pragma unroll
  for (int it = 0; it < NROWS / 1024; ++it)
    atomicAdd(&sh[w][lab[t + it * 1024]], 1);
  __syncthreads();
  if (t < 10) {
    int s = 0;
#pragma unroll
    for (int x = 0; x < 16; ++x) s += sh[x][t];
    hist[t] = s;
  }
  if (t == 10) losssum[0] = 0.f;
}

// ---------------- normalize rows -> bf16 ----------------
__global__ __launch_bounds__(256) void k_norm(const float* __restrict__ f,
                                              __hip_bfloat16* __restrict__ fnb) {
  int wave = threadIdx.x >> 6;
  int lane = threadIdx.x & 63;
  int row = blockIdx.x * 4 + wave;
  const float* src = f + (size_t)row * DIM;
  float v0 = src[lane];
  float v1 = src[lane + 64];
  float ss = v0 * v0 + v1 * v1;
#pragma unroll
  for (int o = 32; o > 0; o >>= 1) ss += __shfl_down(ss, o);
  ss = __shfl(ss, 0);
  float inv = 1.0f / fmaxf(sqrtf(ss), 1e-8f);
  __hip_bfloat16* dst = fnb + (size_t)row * DIM;
  dst[lane] = __float2bfloat16(v0 * inv);
  dst[lane + 64] = __float2bfloat16(v1 * inv);
}

// ---------------- single MFMA pass ----------------
// Block (cs, rsb): rows [rsb*128, +128), cols [cs*1024, +1024) in 8 tiles of 128.
// Per row accumulate: negsum (lab!=), possumE, possumE2, simacc (sum of raw cos dot).
__global__ __launch_bounds__(256, 2) void k_main(
    const ushort* __restrict__ fnb, const int* __restrict__ lab,
    float* __restrict__ pneg, float* __restrict__ ppos,
    float* __restrict__ ppos2, float* __restrict__ psim) {
  __shared__ char lds[BM * 256 + BN * 256];  // A (32KB) + B (32KB), swizzled
  char* Alds = lds;
  char* Blds = lds + BM * 256;

  const int t = threadIdx.x;
  const int lane = t & 63;
  const int w = t >> 6;
  const int wm = w >> 1;  // 0..1  (row half)
  const int wn = w & 1;   // 0..1  (col half)
  const int cs = blockIdx.x;
  const int i0 = blockIdx.y * BM;

  // ---- stage A once (rows i0..i0+127), XOR-swizzled (G4: row-major D=128 bf16) ----
  {
    const int4* src = reinterpret_cast<const int4*>(fnb + (size_t)i0 * DIM);
#pragma unroll
    for (int it = 0; it < 8; ++it) {
      int q = t + 256 * it;       // 0..2047 16B-chunks
      int row = q >> 4, c = q & 15;
      int4 v = src[q];
      *reinterpret_cast<int4*>(Alds + row * 256 + ((c << 4) ^ ((row & 7) << 4))) = v;
    }
  }

  // row labels for this thread's C fragment rows: row = wm*64 + m*16 + (lane>>4)*4 + r
  int lr[4][4];
#pragma unroll
  for (int m = 0; m < 4; ++m)
#pragma unroll
    for (int r = 0; r < 4; ++r)
      lr[m][r] = lab[i0 + wm * 64 + m * 16 + (lane >> 4) * 4 + r];

  float a_neg[4][4] = {}, a_pos[4][4] = {}, a_pos2[4][4] = {}, a_sim[4][4] = {};

  for (int ct = 0; ct < CT_ITERS; ++ct) {
    const int j0 = cs * COLS_PER_SLAB + ct * BN;
    __syncthreads();  // protect Blds from previous iteration's readers
    {
      const int4* src = reinterpret_cast<const int4*>(fnb + (size_t)j0 * DIM);
#pragma unroll
      for (int it = 0; it < 8; ++it) {
        int q = t + 256 * it;
        int row = q >> 4, c = q & 15;
        int4 v = src[q];
        *reinterpret_cast<int4*>(Blds + row * 256 + ((c << 4) ^ ((row & 7) << 4))) = v;
      }
    }
    __syncthreads();

    f32x4 acc[4][4];
#pragma unroll
    for (int m = 0; m < 4; ++m)
#pragma unroll
      for (int n = 0; n < 4; ++n) acc[m][n] = (f32x4){0.f, 0.f, 0.f, 0.f};

#pragma unroll
    for (int ks = 0; ks < 4; ++ks) {
      const int kb = ks * 64 + ((lane >> 4) << 4);  // 16B chunk within 256B row
      bf16x8 af[4], bf[4];
#pragma unroll
      for (int m = 0; m < 4; ++m) {
        int r = wm * 64 + m * 16 + (lane & 15);
        af[m] = *reinterpret_cast<const bf16x8*>(Alds + r * 256 + (kb ^ ((r & 7) << 4)));
      }
#pragma unroll
      for (int n = 0; n < 4; ++n) {
        int r = wn * 64 + n * 16 + (lane & 15);
        bf[n] = *reinterpret_cast<const bf16x8*>(Blds + r * 256 + (kb ^ ((r & 7) << 4)));
      }
#pragma unroll
      for (int m = 0; m < 4; ++m)
#pragma unroll
        for (int n = 0; n < 4; ++n)
          acc[m][n] = __builtin_amdgcn_mfma_f32_16x16x32_bf16(af[m], bf[n], acc[m][n], 0, 0, 0);
    }

    // epilogue: accumulate per-row stats in registers (C: col=lane&15, row=(lane>>4)*4+r)
#pragma unroll
    for (int n = 0; n < 4; ++n) {
      const int lc = lab[j0 + wn * 64 + n * 16 + (lane & 15)];
#pragma unroll
      for (int m = 0; m < 4; ++m)
#pragma unroll
        for (int r = 0; r < 4; ++r) {
          float s = acc[m][n][r];           // cos sim (sim = 2*s)
          float E = __expf(2.0f * s);
          bool pos = (lr[m][r] == lc);
          a_neg[m][r] += pos ? 0.f : E;
          a_pos[m][r] += pos ? E : 0.f;
          a_pos2[m][r] += pos ? E * E : 0.f;
          a_sim[m][r] += pos ? s : 0.f;
        }
    }
  }

  // reduce across the 16 lanes of each row group (cols), then across wn waves via LDS
#pragma unroll
  for (int m = 0; m < 4; ++m)
#pragma unroll
    for (int r = 0; r < 4; ++r)
#pragma unroll
      for (int off = 8; off > 0; off >>= 1) {
        a_neg[m][r] += __shfl_xor(a_neg[m][r], off);
        a_pos[m][r] += __shfl_xor(a_pos[m][r], off);
        a_pos2[m][r] += __shfl_xor(a_pos2[m][r], off);
        a_sim[m][r] += __shfl_xor(a_sim[m][r], off);
      }

  __syncthreads();  // done with A/B tiles; reuse LDS as reduction scratch
  float* red = reinterpret_cast<float*>(lds);  // [128 rows][4]
  const int g = lane >> 4;
  if (wn == 1 && (lane & 15) == 0) {
#pragma unroll
    for (int m = 0; m < 4; ++m)
#pragma unroll
      for (int r = 0; r < 4; ++r) {
        int rl = wm * 64 + m * 16 + g * 4 + r;
        red[rl * 4 + 0] = a_neg[m][r];
        red[rl * 4 + 1] = a_pos[m][r];
        red[rl * 4 + 2] = a_pos2[m][r];
        red[rl * 4 + 3] = a_sim[m][r];
      }
  }
  __syncthreads();
  if (wn == 0 && (lane & 15) == 0) {
#pragma unroll
    for (int m = 0; m < 4; ++m)
#pragma unroll
      for (int r = 0; r < 4; ++r) {
        int rl = wm * 64 + m * 16 + g * 4 + r;
        int row = i0 + rl;
        pneg[cs * NROWS + row] = a_neg[m][r] + red[rl * 4 + 0];
        ppos[cs * NROWS + row] = a_pos[m][r] + red[rl * 4 + 1];
        ppos2[cs * NROWS + row] = a_pos2[m][r] + red[rl * 4 + 2];
        psim[cs * NROWS + row] = a_sim[m][r] + red[rl * 4 + 3];
      }
  }
}

// ---------------- per-row finalize + global sum ----------------
__global__ __launch_bounds__(1024) void k_rowfinal(
    const float* __restrict__ pneg, const float* __restrict__ ppos,
    const float* __restrict__ ppos2, const float* __restrict__ psim,
    const int* __restrict__ lab, const int* __restrict__ hist,
    float* __restrict__ losssum) {
  __shared__ float sred[1024];
  int i = blockIdx.x * 1024 + threadIdx.x;
  float ns = 0.f, ps = 0.f, ps2 = 0.f, sa = 0.f;
#pragma unroll
  for (int cs = 0; cs < CS; ++cs) {
    ns += pneg[cs * NROWS + i];
    ps += ppos[cs * NROWS + i];
    ps2 += ppos2[cs * NROWS + i];
    sa += psim[cs * NROWS + i];
  }
  float cnt = (float)hist[lab[i]];
  float negtot = ns + cnt;  // positives contribute exp(0)=1 each to exp_neg
  // sum over positives: log(negtot) + log1p(E/negtot) - sim,  E=exp(2*cos), sim=2*cos
  float li = cnt * logf(negtot) - 2.f * sa + ps / negtot - ps2 / (2.f * negtot * negtot);
  sred[threadIdx.x] = li;
  __syncthreads();
  for (int s2 = 512; s2 > 0; s2 >>= 1) {
    if (threadIdx.x < s2) sred[threadIdx.x] += sred[threadIdx.x + s2];
    __syncthreads();
  }
  if (threadIdx.x == 0) atomicAdd(losssum, sred[0]);
}

// ---------------- output ----------------
__global__ void k_out(const float* __restrict__ losssum, const int* __restrict__ hist,
                      float* __restrict__ out) {
  if (threadIdx.x == 0) {
    double np = 0.0;
    for (int c = 0; c < 10; ++c) np += (double)hist[c] * (double)hist[c];
    out[0] = (float)((double)losssum[0] / np);
  }
}

extern "C" void kernel_launch(void* const* d_in, const int* in_sizes, int n_in,
                              void* d_out, int out_size, void* d_ws, size_t ws_size,
                              hipStream_t stream) {
  const float* feat = (const float*)d_in[0];
  const int* lab = (const int*)d_in[1];
  float* out = (float*)d_out;

  char* ws = (char*)d_ws;
  __hip_bfloat16* fnb = (__hip_bfloat16*)ws;               // 2 MiB
  size_t off = (size_t)NROWS * DIM * 2;
  float* pneg = (float*)(ws + off);  off += (size_t)CS * NROWS * 4;   // 256 KiB
  float* ppos = (float*)(ws + off);  off += (size_t)CS * NROWS * 4;
  float* ppos2 = (float*)(ws + off); off += (size_t)CS * NROWS * 4;
  float* psim = (float*)(ws + off);  off += (size_t)CS * NROWS * 4;
  int* hist = (int*)(ws + off);      off += 64;
  float* losssum = (float*)(ws + off);

  k_hist<<<1, 1024, 0, stream>>>(lab, hist, losssum);
  k_norm<<<NROWS / 4, 256, 0, stream>>>(feat, fnb);
  dim3 grid(CS, RS);
  k_main<<<grid, 256, 0, stream>>>((const ushort*)fnb, lab, pneg, ppos, ppos2, psim);
  k_rowfinal<<<NROWS / 1024, 1024, 0, stream>>>(pneg, ppos, ppos2, psim, lab, hist, losssum);
  k_out<<<1, 64, 0, stream>>>(losssum, hist, out);
}